// Round 1
// baseline (446.668 us; speedup 1.0000x reference)
//
#include <hip/hip_runtime.h>
#include <stdint.h>
#include <math.h>

#define BB 256
#define VV 128
#define MM 256
#define TDIM 10
#define HH 1024
#define IN_DIM 35840
#define KSPLIT 16
#define KSLICE 2240   /* IN_DIM/KSPLIT */
#define BK 64
#define NCHUNK 35     /* KSLICE/BK */

using f32x4  = __attribute__((ext_vector_type(4))) float;
using bf16x8 = __attribute__((ext_vector_type(8))) short;

__device__ __forceinline__ unsigned short f2bf(float f) {
    unsigned int u = __float_as_uint(f);
    unsigned int r = (u + 0x7FFFu + ((u >> 16) & 1u)) >> 16;
    return (unsigned short)r;
}

__device__ __forceinline__ void gload_lds16(const void* g, void* l) {
    __builtin_amdgcn_global_load_lds(
        (const __attribute__((address_space(1))) unsigned int*)g,
        (__attribute__((address_space(3))) unsigned int*)l,
        16, 0, 0);
}

// ---------------- K1: build pred_input in bf16 -------------------------
__global__ __launch_bounds__(256)
void k_build(const float* __restrict__ x, const float* __restrict__ memory,
             const int* __restrict__ timings, const float* __restrict__ msurp,
             const float* __restrict__ lastp, short* __restrict__ A)
{
    int b = blockIdx.x, t = threadIdx.x;
    __shared__ int t_s[MM], idx_s[MM], st_s[MM];
    __shared__ float red[MM];
    __shared__ float s_surprise;

    // rolled timings: slot0 = 0, slot m = old[m-1]+1
    t_s[t] = (t == 0) ? 0 : timings[b*MM + t - 1] + 1;
    red[t] = (t < VV) ? x[b*VV + t] * lastp[b*VV + t] : 0.f;
    __syncthreads();
    for (int s = 128; s > 0; s >>= 1) {
        if (t < s) red[t] += red[t + s];
        __syncthreads();
    }
    if (t == 0) s_surprise = -logf(red[0] + 1e-8f);

    // stable rank (ascending, ties -> original order)
    int ti = t_s[t], cnt = 0;
    #pragma unroll 4
    for (int j = 0; j < MM; ++j) {
        int tj = t_s[j];
        cnt += (tj < ti) || (tj == ti && j < t);
    }
    idx_s[cnt] = t;
    st_s[cnt]  = ti;
    __syncthreads();

    float invm = 1.f / ((float)st_s[MM-1] + 1.f);
    short* Ab = A + (size_t)b * IN_DIM;
    {
        int st = st_s[t], src = idx_s[t];
        #pragma unroll
        for (int tt = 0; tt < TDIM; ++tt)
            Ab[32768 + t*TDIM + tt] = (short)f2bf((float)((st >> tt) & 1));
        Ab[35328 + t] = (short)f2bf((float)st * invm);
        float sv = (src == 0) ? s_surprise : msurp[b*MM + src - 1] * 0.99f;
        Ab[35584 + t] = (short)f2bf(sv);
    }
    // gather sorted memory rows (rolled: slot0 = x, slot m = memory[m-1])
    int half = t >> 7, v = t & (VV-1);
    for (int p = half; p < MM; p += 2) {
        int src = idx_s[p];
        float val = (src == 0) ? x[b*VV + v]
                               : memory[((size_t)b*MM + src - 1)*VV + v];
        Ab[p*VV + v] = (short)f2bf(val);
    }
}

// ---------------- K2: split-K fused bf16 MFMA GEMM ---------------------
// grid (KSPLIT, 32): x = k-split (XCD locality for shared A slice), y = n-tile.
// BM=256 (full batch), BN=64, BK=64. 256 threads = 4 waves, 64x64 tile/wave.
__global__ __launch_bounds__(256)
void k_gemm(const short* __restrict__ A, const float* __restrict__ W1,
            const float* __restrict__ Wg, float* __restrict__ P)
{
    int ks = blockIdx.x;          // 0..15
    int xt = blockIdx.y;          // 0..31
    const float* W = (xt < 16) ? W1 : Wg;
    int wcol0 = (xt & 15) * 64;
    int pcol0 = xt * 64;          // 0..1984 in the 2048-wide partial
    int k0 = ks * KSLICE;

    __shared__ bf16x8 As8[2048];  // 256 rows x 8 granules (xor-swizzled)
    __shared__ bf16x8 Ws8[512];   // 64 n-rows x 8 granules (W^T, swizzled)

    int t = threadIdx.x;
    int l = t & 63, wv = t >> 6;
    int r = l & 15, q = l >> 4;

    // per-lane LDS frag slots, chunk-invariant
    int aoff[4][2], boff[4][2];
    #pragma unroll
    for (int mt = 0; mt < 4; ++mt)
        #pragma unroll
        for (int s = 0; s < 2; ++s)
            aoff[mt][s] = (wv*64 + mt*16 + r)*8 + ((q + 4*s) ^ (r & 7));
    #pragma unroll
    for (int nt = 0; nt < 4; ++nt)
        #pragma unroll
        for (int s = 0; s < 2; ++s)
            boff[nt][s] = (nt*16 + r)*8 + ((q + 4*s) ^ (r & 7));

    f32x4 acc[4][4];
    #pragma unroll
    for (int mt = 0; mt < 4; ++mt)
        #pragma unroll
        for (int nt = 0; nt < 4; ++nt)
            acc[mt][nt] = (f32x4){0.f, 0.f, 0.f, 0.f};

    int wn  = t & 63;     // W staging: n
    int wq4 = t >> 6;     // W staging: k-quad group

    for (int c = 0; c < NCHUNK; ++c) {
        int kc = k0 + c*BK;
        __syncthreads();   // previous iteration's LDS reads done
        // stage A: 2048 granules, linear slots (writes conflict-free),
        // global addr de-swizzled so slot G holds granule (m, (G&7)^(m&7))
        #pragma unroll
        for (int i = 0; i < 8; ++i) {
            int G = t + i*256;
            int m = G >> 3;
            int kb = (G & 7) ^ (m & 7);
            const short* gp = A + (size_t)m*IN_DIM + kc + kb*8;
            gload_lds16(gp, (void*)(As8 + ((t & ~63) + i*256)));
        }
        // stage W transposed + fp32->bf16
        #pragma unroll
        for (int p4 = 0; p4 < 4; ++p4) {
            int kbase = p4*16 + wq4*4;
            const float* wp = W + (size_t)(kc + kbase)*HH + wcol0 + wn;
            float w0 = wp[0], w1 = wp[HH], w2 = wp[2*HH], w3 = wp[3*HH];
            unsigned int lo = (unsigned int)f2bf(w0) | ((unsigned int)f2bf(w1) << 16);
            unsigned int hi = (unsigned int)f2bf(w2) | ((unsigned int)f2bf(w3) << 16);
            int kb = kbase >> 3, hf = (kbase >> 2) & 1;
            unsigned int* dst = (unsigned int*)((short*)Ws8 +
                                ((wn*8 + (kb ^ (wn & 7)))*8 + hf*4));
            dst[0] = lo; dst[1] = hi;
        }
        __syncthreads();   // drains vmcnt (global_load_lds) + lgkm

        #pragma unroll
        for (int s = 0; s < 2; ++s) {
            bf16x8 af[4], bfr[4];
            #pragma unroll
            for (int mt = 0; mt < 4; ++mt) af[mt] = As8[aoff[mt][s]];
            #pragma unroll
            for (int nt = 0; nt < 4; ++nt) bfr[nt] = Ws8[boff[nt][s]];
            #pragma unroll
            for (int mt = 0; mt < 4; ++mt)
                #pragma unroll
                for (int nt = 0; nt < 4; ++nt)
                    acc[mt][nt] = __builtin_amdgcn_mfma_f32_16x16x32_bf16(
                        af[mt], bfr[nt], acc[mt][nt], 0, 0, 0);
        }
    }

    // epilogue: partials P[ks][m][2048]
    #pragma unroll
    for (int mt = 0; mt < 4; ++mt)
        #pragma unroll
        for (int nt = 0; nt < 4; ++nt)
            #pragma unroll
            for (int rg = 0; rg < 4; ++rg) {
                int m = wv*64 + mt*16 + q*4 + rg;
                int n = pcol0 + nt*16 + r;
                P[((size_t)ks*BB + m)*2048 + n] = acc[mt][nt][rg];
            }
}

// ---------------- K3: split-K reduce + bias + sigmoid gate -------------
__global__ __launch_bounds__(256)
void k_reduce(const float* __restrict__ P, const float* __restrict__ b1,
              const float* __restrict__ bg, float* __restrict__ h)
{
    int id = blockIdx.x * 256 + threadIdx.x;   // 0..262143
    int b = id >> 10, j = id & 1023;
    float p1 = b1[j], pg = bg[j];
    #pragma unroll
    for (int ks = 0; ks < KSPLIT; ++ks) {
        size_t base = ((size_t)ks*BB + b)*2048;
        p1 += P[base + j];
        pg += P[base + 1024 + j];
    }
    float g = 1.f / (1.f + expf(-pg));
    h[(size_t)b*HH + j] = p1 * g;
}

// ---------------- K4: h @ W2 + b2 --------------------------------------
__global__ __launch_bounds__(512)
void k_out(const float* __restrict__ h, const float* __restrict__ W2,
           const float* __restrict__ b2, float* __restrict__ out)
{
    int t = threadIdx.x;
    int v = t & 127, bi = t >> 7;
    int b = blockIdx.x * 4 + bi;
    const float* hb = h + (size_t)b*HH;
    float acc = b2[v];
    #pragma unroll 8
    for (int k = 0; k < HH; ++k)
        acc += hb[k] * W2[k*VV + v];
    out[(size_t)b*VV + v] = acc;
}

extern "C" void kernel_launch(void* const* d_in, const int* in_sizes, int n_in,
                              void* d_out, int out_size, void* d_ws, size_t ws_size,
                              hipStream_t stream)
{
    const float* x    = (const float*)d_in[0];
    const float* mem  = (const float*)d_in[1];
    const int*   tim  = (const int*)d_in[2];
    const float* msur = (const float*)d_in[3];
    const float* lp   = (const float*)d_in[4];
    const float* W1   = (const float*)d_in[5];
    const float* b1   = (const float*)d_in[6];
    const float* Wg   = (const float*)d_in[7];
    const float* bg   = (const float*)d_in[8];
    const float* W2   = (const float*)d_in[9];
    const float* b2   = (const float*)d_in[10];
    float* out = (float*)d_out;

    // ws layout: A bf16 [256][35840] | P fp32 [16][256][2048] | h fp32 [256][1024]
    short* A = (short*)d_ws;
    float* P = (float*)((char*)d_ws + 18350080);
    float* h = (float*)((char*)d_ws + 51904512);

    k_build <<<256, 256, 0, stream>>>(x, mem, tim, msur, lp, A);
    k_gemm  <<<dim3(KSPLIT, 32), 256, 0, stream>>>(A, W1, Wg, P);
    k_reduce<<<1024, 256, 0, stream>>>(P, b1, bg, h);
    k_out   <<<64, 512, 0, stream>>>(h, W2, b2, out);
}

// Round 2
// 439.609 us; speedup vs baseline: 1.0161x; 1.0161x over previous
//
#include <hip/hip_runtime.h>
#include <stdint.h>
#include <math.h>

#define BB 256
#define VV 128
#define MM 256
#define TDIM 10
#define HH 1024
#define IN_DIM 35840
#define KSPLIT 16
#define KSLICE 2240   /* IN_DIM/KSPLIT */
#define BK 64
#define NCHUNK 35     /* KSLICE/BK */

using f32x4  = __attribute__((ext_vector_type(4))) float;
using bf16x8 = __attribute__((ext_vector_type(8))) short;

__device__ __forceinline__ unsigned short f2bf(float f) {
    unsigned int u = __float_as_uint(f);
    unsigned int r = (u + 0x7FFFu + ((u >> 16) & 1u)) >> 16;
    return (unsigned short)r;
}

__device__ __forceinline__ void gload_lds16(const void* g, void* l) {
    __builtin_amdgcn_global_load_lds(
        (const __attribute__((address_space(1))) unsigned int*)g,
        (__attribute__((address_space(3))) unsigned int*)l,
        16, 0, 0);
}

// ---------------- K1: build pred_input in bf16 -------------------------
__global__ __launch_bounds__(256)
void k_build(const float* __restrict__ x, const float* __restrict__ memory,
             const int* __restrict__ timings, const float* __restrict__ msurp,
             const float* __restrict__ lastp, short* __restrict__ A)
{
    int b = blockIdx.x, t = threadIdx.x;
    __shared__ int t_s[MM], idx_s[MM], st_s[MM];
    __shared__ float red[MM];
    __shared__ float s_surprise;

    // rolled timings: slot0 = 0, slot m = old[m-1]+1
    t_s[t] = (t == 0) ? 0 : timings[b*MM + t - 1] + 1;
    red[t] = (t < VV) ? x[b*VV + t] * lastp[b*VV + t] : 0.f;
    __syncthreads();
    for (int s = 128; s > 0; s >>= 1) {
        if (t < s) red[t] += red[t + s];
        __syncthreads();
    }
    if (t == 0) s_surprise = -logf(red[0] + 1e-8f);

    // stable rank (ascending, ties -> original order)
    int ti = t_s[t], cnt = 0;
    #pragma unroll 4
    for (int j = 0; j < MM; ++j) {
        int tj = t_s[j];
        cnt += (tj < ti) || (tj == ti && j < t);
    }
    idx_s[cnt] = t;
    st_s[cnt]  = ti;
    __syncthreads();

    float invm = 1.f / ((float)st_s[MM-1] + 1.f);
    short* Ab = A + (size_t)b * IN_DIM;
    {
        int st = st_s[t], src = idx_s[t];
        #pragma unroll
        for (int tt = 0; tt < TDIM; ++tt)
            Ab[32768 + t*TDIM + tt] = (short)f2bf((float)((st >> tt) & 1));
        Ab[35328 + t] = (short)f2bf((float)st * invm);
        float sv = (src == 0) ? s_surprise : msurp[b*MM + src - 1] * 0.99f;
        Ab[35584 + t] = (short)f2bf(sv);
    }
    // gather sorted memory rows (rolled: slot0 = x, slot m = memory[m-1])
    int half = t >> 7, v = t & (VV-1);
    for (int p = half; p < MM; p += 2) {
        int src = idx_s[p];
        float val = (src == 0) ? x[b*VV + v]
                               : memory[((size_t)b*MM + src - 1)*VV + v];
        Ab[p*VV + v] = (short)f2bf(val);
    }
}

// ---------------- K2: split-K fused bf16 MFMA GEMM ---------------------
// grid (KSPLIT=16, 64): x = k-split (XCD locality: linear%8 = x%8 so same-ks
// blocks share an XCD L2 for the A slice), y = n-tile of 32.
// BM=256 (full batch), BN=32, BK=64. 256 threads = 4 waves, 64x32 tile/wave.
// 36 KB LDS -> 4 blocks/CU; W fp32 loads register-prefetched one chunk ahead.
__global__ __launch_bounds__(256, 4)
void k_gemm(const short* __restrict__ A, const float* __restrict__ W1,
            const float* __restrict__ Wg, float* __restrict__ P)
{
    int ks = blockIdx.x;          // 0..15
    int xt = blockIdx.y;          // 0..63
    const float* W = (xt < 32) ? W1 : Wg;
    int wcol0 = (xt & 31) * 32;
    int pcol0 = xt * 32;          // 0..2016 in the 2048-wide partial
    int k0 = ks * KSLICE;

    __shared__ bf16x8 As8[2048];  // 256 rows x 8 granules (xor-swizzled) 32 KB
    __shared__ bf16x8 Ws8[256];   // 32 n-rows x 8 granules (W^T, swizzled) 4 KB

    int t = threadIdx.x;
    int l = t & 63, wv = t >> 6;
    int r = l & 15, q = l >> 4;

    // per-lane LDS frag slots, chunk-invariant
    int aoff[4][2], boff[2][2];
    #pragma unroll
    for (int mt = 0; mt < 4; ++mt)
        #pragma unroll
        for (int s = 0; s < 2; ++s)
            aoff[mt][s] = (wv*64 + mt*16 + r)*8 + ((q + 4*s) ^ (r & 7));
    #pragma unroll
    for (int nt = 0; nt < 2; ++nt)
        #pragma unroll
        for (int s = 0; s < 2; ++s)
            boff[nt][s] = (nt*16 + r)*8 + ((q + 4*s) ^ (r & 7));

    f32x4 acc[4][2];
    #pragma unroll
    for (int mt = 0; mt < 4; ++mt)
        #pragma unroll
        for (int nt = 0; nt < 2; ++nt)
            acc[mt][nt] = (f32x4){0.f, 0.f, 0.f, 0.f};

    // W staging assignment: thread t -> (n = t&31, kg = t>>5), one 8-k granule
    int wn = t & 31, wkg = t >> 5;
    const float* wbase = W + (size_t)(k0 + wkg*8)*HH + wcol0 + wn;

    float wreg[8];
    #pragma unroll
    for (int j = 0; j < 8; ++j) wreg[j] = wbase[(size_t)j*HH];   // prefetch c=0

    for (int c = 0; c < NCHUNK; ++c) {
        int kc = k0 + c*BK;
        __syncthreads();   // sync1: prior compute done; wreg(c) loads drained
        // convert prefetched W(c) -> Ws (one b128, bank-balanced slot)
        {
            union { bf16x8 v; unsigned int d[4]; } u;
            #pragma unroll
            for (int j = 0; j < 4; ++j)
                u.d[j] = (unsigned int)f2bf(wreg[2*j]) |
                         ((unsigned int)f2bf(wreg[2*j+1]) << 16);
            Ws8[wn*8 + (wkg ^ (wn & 7))] = u.v;
        }
        // stage A(c): 2048 granules via lds-dma, slot G holds (m, (G&7)^(m&7))
        #pragma unroll
        for (int i = 0; i < 8; ++i) {
            int G = t + i*256;
            int m = G >> 3;
            int kb = (G & 7) ^ (m & 7);
            const short* gp = A + (size_t)m*IN_DIM + kc + kb*8;
            gload_lds16(gp, (void*)(As8 + ((t & ~63) + i*256)));
        }
        // issue W(c+1) prefetch now so its latency overlaps the A-dma drain
        {
            int cn = (c + 1 < NCHUNK) ? c + 1 : c;
            const float* wp = wbase + (size_t)cn*BK*HH;
            #pragma unroll
            for (int j = 0; j < 8; ++j) wreg[j] = wp[(size_t)j*HH];
        }
        __syncthreads();   // sync2: drains A-dma (+ in-flight W prefetch)

        #pragma unroll
        for (int s = 0; s < 2; ++s) {
            bf16x8 af[4], bfr[2];
            #pragma unroll
            for (int mt = 0; mt < 4; ++mt) af[mt] = As8[aoff[mt][s]];
            #pragma unroll
            for (int nt = 0; nt < 2; ++nt) bfr[nt] = Ws8[boff[nt][s]];
            #pragma unroll
            for (int mt = 0; mt < 4; ++mt)
                #pragma unroll
                for (int nt = 0; nt < 2; ++nt)
                    acc[mt][nt] = __builtin_amdgcn_mfma_f32_16x16x32_bf16(
                        af[mt], bfr[nt], acc[mt][nt], 0, 0, 0);
        }
    }

    // epilogue: partials P[ks][m][2048]
    #pragma unroll
    for (int mt = 0; mt < 4; ++mt)
        #pragma unroll
        for (int nt = 0; nt < 2; ++nt)
            #pragma unroll
            for (int rg = 0; rg < 4; ++rg) {
                int m = wv*64 + mt*16 + q*4 + rg;
                int n = pcol0 + nt*16 + r;
                P[((size_t)ks*BB + m)*2048 + n] = acc[mt][nt][rg];
            }
}

// ---------------- K3: split-K reduce + bias + sigmoid gate -------------
__global__ __launch_bounds__(256)
void k_reduce(const float* __restrict__ P, const float* __restrict__ b1,
              const float* __restrict__ bg, float* __restrict__ h)
{
    int id = blockIdx.x * 256 + threadIdx.x;   // 0..262143
    int b = id >> 10, j = id & 1023;
    float p1 = b1[j], pg = bg[j];
    #pragma unroll
    for (int ks = 0; ks < KSPLIT; ++ks) {
        size_t base = ((size_t)ks*BB + b)*2048;
        p1 += P[base + j];
        pg += P[base + 1024 + j];
    }
    float g = 1.f / (1.f + expf(-pg));
    h[(size_t)b*HH + j] = p1 * g;
}

// ---------------- K4: h @ W2 + b2 (one batch row per block) ------------
__global__ __launch_bounds__(256)
void k_out(const float* __restrict__ h, const float* __restrict__ W2,
           const float* __restrict__ b2, float* __restrict__ out)
{
    int b = blockIdx.x, t = threadIdx.x;
    int v = t & 127, kh = t >> 7;          // k-split by 2
    const float* hb = h + (size_t)b*HH + kh*512;
    const float* wp = W2 + (size_t)kh*512*VV + v;
    float acc = 0.f;
    #pragma unroll 8
    for (int k = 0; k < 512; ++k)
        acc += hb[k] * wp[(size_t)k*VV];
    __shared__ float s[256];
    s[t] = acc;
    __syncthreads();
    if (t < 128)
        out[(size_t)b*VV + v] = s[t] + s[t + 128] + b2[v];
}

extern "C" void kernel_launch(void* const* d_in, const int* in_sizes, int n_in,
                              void* d_out, int out_size, void* d_ws, size_t ws_size,
                              hipStream_t stream)
{
    const float* x    = (const float*)d_in[0];
    const float* mem  = (const float*)d_in[1];
    const int*   tim  = (const int*)d_in[2];
    const float* msur = (const float*)d_in[3];
    const float* lp   = (const float*)d_in[4];
    const float* W1   = (const float*)d_in[5];
    const float* b1   = (const float*)d_in[6];
    const float* Wg   = (const float*)d_in[7];
    const float* bg   = (const float*)d_in[8];
    const float* W2   = (const float*)d_in[9];
    const float* b2   = (const float*)d_in[10];
    float* out = (float*)d_out;

    // ws layout: A bf16 [256][35840] | P fp32 [16][256][2048] | h fp32 [256][1024]
    short* A = (short*)d_ws;
    float* P = (float*)((char*)d_ws + 18350080);
    float* h = (float*)((char*)d_ws + 51904512);

    k_build <<<256, 256, 0, stream>>>(x, mem, tim, msur, lp, A);
    k_gemm  <<<dim3(KSPLIT, 64), 256, 0, stream>>>(A, W1, Wg, P);
    k_reduce<<<1024, 256, 0, stream>>>(P, b1, bg, h);
    k_out   <<<256, 256, 0, stream>>>(h, W2, b2, out);
}

// Round 3
// 435.551 us; speedup vs baseline: 1.0255x; 1.0093x over previous
//
#include <hip/hip_runtime.h>
#include <stdint.h>
#include <math.h>

#define BB 256
#define VV 128
#define MM 256
#define TDIM 10
#define HH 1024
#define IN_DIM 35840
#define KSPLIT 16
#define KSLICE 2240   /* IN_DIM/KSPLIT */
#define BK 32
#define NCHUNK 70     /* KSLICE/BK */

using f32x4  = __attribute__((ext_vector_type(4))) float;
using bf16x8 = __attribute__((ext_vector_type(8))) short;

__device__ __forceinline__ unsigned short f2bf(float f) {
    unsigned int u = __float_as_uint(f);
    unsigned int r = (u + 0x7FFFu + ((u >> 16) & 1u)) >> 16;
    return (unsigned short)r;
}

__device__ __forceinline__ void gload_lds16(const void* g, void* l) {
    __builtin_amdgcn_global_load_lds(
        (const __attribute__((address_space(1))) unsigned int*)g,
        (__attribute__((address_space(3))) unsigned int*)l,
        16, 0, 0);
}

// ---------------- K1: build pred_input in bf16 -------------------------
__global__ __launch_bounds__(256)
void k_build(const float* __restrict__ x, const float* __restrict__ memory,
             const int* __restrict__ timings, const float* __restrict__ msurp,
             const float* __restrict__ lastp, short* __restrict__ A)
{
    int b = blockIdx.x, t = threadIdx.x;
    __shared__ int t_s[MM], idx_s[MM], st_s[MM];
    __shared__ float red[MM];
    __shared__ float s_surprise;

    t_s[t] = (t == 0) ? 0 : timings[b*MM + t - 1] + 1;
    red[t] = (t < VV) ? x[b*VV + t] * lastp[b*VV + t] : 0.f;
    __syncthreads();
    for (int s = 128; s > 0; s >>= 1) {
        if (t < s) red[t] += red[t + s];
        __syncthreads();
    }
    if (t == 0) s_surprise = -logf(red[0] + 1e-8f);

    int ti = t_s[t], cnt = 0;
    #pragma unroll 4
    for (int j = 0; j < MM; ++j) {
        int tj = t_s[j];
        cnt += (tj < ti) || (tj == ti && j < t);
    }
    idx_s[cnt] = t;
    st_s[cnt]  = ti;
    __syncthreads();

    float invm = 1.f / ((float)st_s[MM-1] + 1.f);
    short* Ab = A + (size_t)b * IN_DIM;
    {
        int st = st_s[t], src = idx_s[t];
        #pragma unroll
        for (int tt = 0; tt < TDIM; ++tt)
            Ab[32768 + t*TDIM + tt] = (short)f2bf((float)((st >> tt) & 1));
        Ab[35328 + t] = (short)f2bf((float)st * invm);
        float sv = (src == 0) ? s_surprise : msurp[b*MM + src - 1] * 0.99f;
        Ab[35584 + t] = (short)f2bf(sv);
    }
    int half = t >> 7, v = t & (VV-1);
    for (int p = half; p < MM; p += 2) {
        int src = idx_s[p];
        float val = (src == 0) ? x[b*VV + v]
                               : memory[((size_t)b*MM + src - 1)*VV + v];
        Ab[p*VV + v] = (short)f2bf(val);
    }
}

// ---------------- K2: split-K fused bf16 MFMA GEMM, double-buffered ----
// grid (16, 32): x = k-split, y = n-tile of 64 (xt<16 -> W1, else Wg).
// 512 threads = 8 waves; wave (wv&3) covers m-rows, (wv>>2) covers n-half.
// BM=256, BN=64, BK=32. LDS: As[2][1024]x16B=32K + Ws[2][256]x16B=8K = 40KB.
// One barrier per chunk; ALL vmem (A-dma c+1, W loads c+2) issued before the
// MFMA block so the drain at the barrier is covered by compute.
__global__ __launch_bounds__(512, 4)
void k_gemm(const short* __restrict__ A, const float* __restrict__ W1,
            const float* __restrict__ Wg, float* __restrict__ P)
{
    int ks = blockIdx.x;          // 0..15
    int xt = blockIdx.y;          // 0..31
    const float* W = (xt < 16) ? W1 : Wg;
    int wcol0 = (xt & 15) * 64;
    int pcol0 = xt * 64;
    int k0 = ks * KSLICE;

    __shared__ bf16x8 As8[2][1024];
    __shared__ bf16x8 Ws8[2][256];

    int t = threadIdx.x;
    int l = t & 63, wv = t >> 6;          // wv 0..7
    int r = l & 15, q = l >> 4;
    int wm = wv & 3, nh = wv >> 2;

    // frag slots (chunk-invariant): row R, granule q, swizzle q^((R>>1)&3)
    int aoff[4], boff[2];
    #pragma unroll
    for (int mt = 0; mt < 4; ++mt) {
        int R = wm*64 + mt*16 + r;
        aoff[mt] = R*4 + (q ^ ((R >> 1) & 3));
    }
    #pragma unroll
    for (int nt = 0; nt < 2; ++nt) {
        int R = nh*32 + nt*16 + r;
        boff[nt] = R*4 + (q ^ ((R >> 1) & 3));
    }

    f32x4 acc[4][2];
    #pragma unroll
    for (int mt = 0; mt < 4; ++mt)
        #pragma unroll
        for (int nt = 0; nt < 2; ++nt)
            acc[mt][nt] = (f32x4){0.f, 0.f, 0.f, 0.f};

    // W staging: thread -> (n = l, k-quad = wv): 4 floats, k = kc + wv*4 + j
    int wn = l;
    int wkg = wv >> 1, whalf = wv & 1;    // granule, 8B half
    int wslot16 = (wn*4 + (wkg ^ ((wn >> 1) & 3))) * 16 + whalf * 8;
    const float* wbase = W + (size_t)(k0 + wv*4)*HH + wcol0 + wn;
    float wreg[4];

    // ---- prologue: W(0) -> Ws[0]; A(0) dma; W(1) -> wreg ----
    #pragma unroll
    for (int j = 0; j < 4; ++j) wreg[j] = wbase[(size_t)j*HH];
    {
        unsigned int lo = (unsigned int)f2bf(wreg[0]) | ((unsigned int)f2bf(wreg[1]) << 16);
        unsigned int hi = (unsigned int)f2bf(wreg[2]) | ((unsigned int)f2bf(wreg[3]) << 16);
        unsigned int* dst = (unsigned int*)((char*)&Ws8[0][0] + wslot16);
        dst[0] = lo; dst[1] = hi;
    }
    #pragma unroll
    for (int i = 0; i < 2; ++i) {
        int G = t + i*512;
        int m = G >> 2;
        int kb = (G & 3) ^ ((m >> 1) & 3);
        gload_lds16(A + (size_t)m*IN_DIM + k0 + kb*8,
                    (void*)(&As8[0][0] + (t & ~63) + i*512));
    }
    #pragma unroll
    for (int j = 0; j < 4; ++j) wreg[j] = wbase[(size_t)(BK*HH) + (size_t)j*HH];
    __syncthreads();

    for (int c = 0; c < NCHUNK; ++c) {
        int pb = c & 1, pn = pb ^ 1;
        // convert wreg (= W(c+1)) into Ws[pn]
        {
            unsigned int lo = (unsigned int)f2bf(wreg[0]) | ((unsigned int)f2bf(wreg[1]) << 16);
            unsigned int hi = (unsigned int)f2bf(wreg[2]) | ((unsigned int)f2bf(wreg[3]) << 16);
            unsigned int* dst = (unsigned int*)((char*)&Ws8[pn][0] + wslot16);
            dst[0] = lo; dst[1] = hi;
        }
        // issue A-dma(c+1) -> As[pn]
        {
            int cA = (c + 1 < NCHUNK) ? c + 1 : c;
            int kc = k0 + cA*BK;
            #pragma unroll
            for (int i = 0; i < 2; ++i) {
                int G = t + i*512;
                int m = G >> 2;
                int kb = (G & 3) ^ ((m >> 1) & 3);
                gload_lds16(A + (size_t)m*IN_DIM + kc + kb*8,
                            (void*)(&As8[pn][0] + (t & ~63) + i*512));
            }
        }
        // issue W(c+2) -> wreg
        {
            int cW = (c + 2 < NCHUNK) ? c + 2 : NCHUNK - 1;
            const float* wp = wbase + (size_t)cW*BK*HH;
            #pragma unroll
            for (int j = 0; j < 4; ++j) wreg[j] = wp[(size_t)j*HH];
        }
        // compute chunk c
        {
            bf16x8 af[4], bfr[2];
            #pragma unroll
            for (int mt = 0; mt < 4; ++mt) af[mt] = As8[pb][aoff[mt]];
            #pragma unroll
            for (int nt = 0; nt < 2; ++nt) bfr[nt] = Ws8[pb][boff[nt]];
            #pragma unroll
            for (int mt = 0; mt < 4; ++mt)
                #pragma unroll
                for (int nt = 0; nt < 2; ++nt)
                    acc[mt][nt] = __builtin_amdgcn_mfma_f32_16x16x32_bf16(
                        af[mt], bfr[nt], acc[mt][nt], 0, 0, 0);
        }
        __syncthreads();   // drains A-dma(c+1) + W(c+2); all covered by compute
    }

    // epilogue: partials P[ks][m][2048]
    #pragma unroll
    for (int mt = 0; mt < 4; ++mt)
        #pragma unroll
        for (int nt = 0; nt < 2; ++nt)
            #pragma unroll
            for (int rg = 0; rg < 4; ++rg) {
                int m = wm*64 + mt*16 + q*4 + rg;
                int n = pcol0 + nh*32 + nt*16 + r;
                P[((size_t)ks*BB + m)*2048 + n] = acc[mt][nt][rg];
            }
}

// ---------------- K3: split-K reduce + bias + sigmoid gate (float4) ----
__global__ __launch_bounds__(256)
void k_reduce(const float* __restrict__ P, const float* __restrict__ b1,
              const float* __restrict__ bg, float* __restrict__ h)
{
    int b = blockIdx.x, t = threadIdx.x;       // t indexes 4-wide j groups
    const f32x4* P4 = (const f32x4*)P;
    f32x4 p1 = ((const f32x4*)b1)[t];
    f32x4 pg = ((const f32x4*)bg)[t];
    #pragma unroll
    for (int ks = 0; ks < KSPLIT; ++ks) {
        size_t base = ((size_t)ks*BB + b) * 512;   // 2048 floats / 4
        p1 += P4[base + t];
        pg += P4[base + 256 + t];
    }
    f32x4 o;
    #pragma unroll
    for (int j = 0; j < 4; ++j)
        o[j] = p1[j] / (1.f + expf(-pg[j]));
    ((f32x4*)h)[(size_t)b*256 + t] = o;
}

// ---------------- K4: h @ W2 + b2 (one batch row per block) ------------
__global__ __launch_bounds__(256)
void k_out(const float* __restrict__ h, const float* __restrict__ W2,
           const float* __restrict__ b2, float* __restrict__ out)
{
    int b = blockIdx.x, t = threadIdx.x;
    int v = t & 127, kh = t >> 7;          // k-split by 2
    const float* hb = h + (size_t)b*HH + kh*512;
    const float* wp = W2 + (size_t)kh*512*VV + v;
    float acc = 0.f;
    #pragma unroll 8
    for (int k = 0; k < 512; ++k)
        acc += hb[k] * wp[(size_t)k*VV];
    __shared__ float s[256];
    s[t] = acc;
    __syncthreads();
    if (t < 128)
        out[(size_t)b*VV + v] = s[t] + s[t + 128] + b2[v];
}

extern "C" void kernel_launch(void* const* d_in, const int* in_sizes, int n_in,
                              void* d_out, int out_size, void* d_ws, size_t ws_size,
                              hipStream_t stream)
{
    const float* x    = (const float*)d_in[0];
    const float* mem  = (const float*)d_in[1];
    const int*   tim  = (const int*)d_in[2];
    const float* msur = (const float*)d_in[3];
    const float* lp   = (const float*)d_in[4];
    const float* W1   = (const float*)d_in[5];
    const float* b1   = (const float*)d_in[6];
    const float* Wg   = (const float*)d_in[7];
    const float* bg   = (const float*)d_in[8];
    const float* W2   = (const float*)d_in[9];
    const float* b2   = (const float*)d_in[10];
    float* out = (float*)d_out;

    // ws layout: A bf16 [256][35840] | P fp32 [16][256][2048] | h fp32 [256][1024]
    short* A = (short*)d_ws;
    float* P = (float*)((char*)d_ws + 18350080);
    float* h = (float*)((char*)d_ws + 51904512);

    k_build <<<256, 256, 0, stream>>>(x, mem, tim, msur, lp, A);
    k_gemm  <<<dim3(KSPLIT, 32), 512, 0, stream>>>(A, W1, Wg, P);
    k_reduce<<<256, 256, 0, stream>>>(P, b1, bg, h);
    k_out   <<<256, 256, 0, stream>>>(h, W2, b2, out);
}